// Round 16
// baseline (126.319 us; speedup 1.0000x reference)
//
#include <hip/hip_runtime.h>
#include <math.h>

#define Bdim 2048
#define Hdim 256
#define KS 32
#define Udim 128
#define OBSD 128
#define PROJD 128
#define H3 768

__device__ __forceinline__ float sigm(float x){ return 1.0f/(1.0f+__expf(-x)); }

typedef float __attribute__((ext_vector_type(4))) f32x4;

__device__ __forceinline__ float4 ntload4(const float* p){
    f32x4 v = __builtin_nontemporal_load((const f32x4*)p);
    return make_float4(v.x, v.y, v.z, v.w);
}

// ---------------- Kernel A1 (R15 exact): 4 rows/block, 512 blocks ----------------
__global__ __launch_bounds__(256) void kA1(
    const float* __restrict__ obs, const float* __restrict__ ssum,
    const float* __restrict__ W_obs, const float* __restrict__ b_obs,
    const float* __restrict__ W_ssum, const float* __restrict__ b_ssum,
    float* __restrict__ xin)
{
    __shared__ float s_in[2][4][128];
    const int t = threadIdx.x;
    const int r0 = blockIdx.x * 4;

    {
        int src = t >> 7, r = (t >> 5) & 3, c4 = (t & 31) << 2;
        const float* base = src ? ssum : obs;
        float4 v = *(const float4*)(base + (size_t)(r0+r)*OBSD + c4);
        s_in[src][r][c4+0]=v.x; s_in[src][r][c4+1]=v.y;
        s_in[src][r][c4+2]=v.z; s_in[src][r][c4+3]=v.w;
    }
    __syncthreads();

    const int col = t & 127;
    const int src = t >> 7;
    const float* Wp = src ? W_ssum : W_obs;
    const float bb = src ? b_ssum[col] : b_obs[col];

    float acc[4] = {0,0,0,0};
    for (int i=0;i<128;i++){
        float w = Wp[i*PROJD + col];
        #pragma unroll
        for (int r=0;r<4;r++) acc[r] = fmaf(s_in[src][r][i], w, acc[r]);
    }
    #pragma unroll
    for (int r=0;r<4;r++)
        xin[(size_t)(r0+r)*256 + t] = tanhf(acc[r] + bb);
}

// ---------------- Kernel G2: 64x64 tiles, 256 thr, 512 blocks, K-chunk 32 double-buffered -----
__global__ __launch_bounds__(256) void kG2(
    const float* __restrict__ xin, const float* __restrict__ hp,
    const float* __restrict__ Wi, const float* __restrict__ Wh,
    float* __restrict__ g)
{
    __shared__ float Xt[2][32][68];    // [buf][kk][row], transposed, padded
    __shared__ float Wt[2][32][64];

    const int t = threadIdx.x;
    const int bx = blockIdx.x >> 4;        // 0..31
    const int by = blockIdx.x & 15;        // 0..15
    const int r0 = bx * 64;
    const int c0 = by * 64;

    const int kbeg = (c0 >= 768) ? 256 : 0;
    const int kend = (c0 >= 512 && c0 < 768) ? 256 : 512;
    const int nck  = (kend - kbeg) >> 5;

    const int cW  = (c0 < 512) ? c0 : (c0 - 256);
    const int rowA = (t & 15) << 2;
    const int colA = (t >> 4) << 2;

    // staging maps (2 float4 per thread per tile)
    const int xrow0 = (2*t+0) >> 3, xk40 = ((2*t+0) & 7) << 2;
    const int xrow1 = (2*t+1) >> 3, xk41 = ((2*t+1) & 7) << 2;
    const int wk0 = (2*t+0) >> 4, wc40 = ((2*t+0) & 15) << 2;
    const int wk1 = (2*t+1) >> 4, wc41 = ((2*t+1) & 15) << 2;

    float acc[4][4] = {{0.f}};
    float4 xr0, xr1, wr0, wr1;

    #define LOADX(row, k4, k0) \
        ( ((k0)+(k4)) < 256 ? *(const float4*)(xin + (size_t)(r0+(row))*256 + (k0)+(k4)) \
                            : *(const float4*)(hp  + (size_t)(r0+(row))*256 + (k0)+(k4)-256) )
    #define LOADW(wk, wc4, k0) \
        ( ((k0)+(wk)) < 256 ? *(const float4*)(Wi + (size_t)((k0)+(wk))*H3 + c0 + (wc4)) \
                            : *(const float4*)(Wh + (size_t)((k0)+(wk)-256)*H3 + cW + (wc4)) )

    {
        const int k0 = kbeg;
        xr0 = LOADX(xrow0, xk40, k0);
        xr1 = LOADX(xrow1, xk41, k0);
        wr0 = LOADW(wk0, wc40, k0);
        wr1 = LOADW(wk1, wc41, k0);
    }
    Xt[0][xk40+0][xrow0]=xr0.x; Xt[0][xk40+1][xrow0]=xr0.y; Xt[0][xk40+2][xrow0]=xr0.z; Xt[0][xk40+3][xrow0]=xr0.w;
    Xt[0][xk41+0][xrow1]=xr1.x; Xt[0][xk41+1][xrow1]=xr1.y; Xt[0][xk41+2][xrow1]=xr1.z; Xt[0][xk41+3][xrow1]=xr1.w;
    *(float4*)&Wt[0][wk0][wc40] = wr0;
    *(float4*)&Wt[0][wk1][wc41] = wr1;
    __syncthreads();

    for (int ck = 0; ck < nck; ck++){
        const int cur = ck & 1;
        const bool more = (ck + 1 < nck);
        if (more){
            const int k0 = kbeg + ((ck + 1) << 5);
            xr0 = LOADX(xrow0, xk40, k0);
            xr1 = LOADX(xrow1, xk41, k0);
            wr0 = LOADW(wk0, wc40, k0);
            wr1 = LOADW(wk1, wc41, k0);
        }
        #pragma unroll
        for (int kk = 0; kk < 32; kk++){
            float4 a4 = *(const float4*)&Xt[cur][kk][rowA];
            float4 b4 = *(const float4*)&Wt[cur][kk][colA];
            float av[4] = {a4.x, a4.y, a4.z, a4.w};
            float bv[4] = {b4.x, b4.y, b4.z, b4.w};
            #pragma unroll
            for (int i=0;i<4;i++)
                #pragma unroll
                for (int j=0;j<4;j++)
                    acc[i][j] = fmaf(av[i], bv[j], acc[i][j]);
        }
        if (more){
            const int nxt = cur ^ 1;
            Xt[nxt][xk40+0][xrow0]=xr0.x; Xt[nxt][xk40+1][xrow0]=xr0.y; Xt[nxt][xk40+2][xrow0]=xr0.z; Xt[nxt][xk40+3][xrow0]=xr0.w;
            Xt[nxt][xk41+0][xrow1]=xr1.x; Xt[nxt][xk41+1][xrow1]=xr1.y; Xt[nxt][xk41+2][xrow1]=xr1.z; Xt[nxt][xk41+3][xrow1]=xr1.w;
            *(float4*)&Wt[nxt][wk0][wc40] = wr0;
            *(float4*)&Wt[nxt][wk1][wc41] = wr1;
            __syncthreads();
        }
    }
    #undef LOADX
    #undef LOADW

    #pragma unroll
    for (int i=0;i<4;i++){
        float4 o = make_float4(acc[i][0], acc[i][1], acc[i][2], acc[i][3]);
        *(float4*)&g[(size_t)(r0 + rowA + i)*1024 + c0 + colA] = o;
    }
}

// ---------------- Kernel A3 (R12 exact): 4 rows/block, float4 W_mean GEMV ----------------
__global__ __launch_bounds__(256) void kA3(
    const float* __restrict__ g, const float* __restrict__ h_prev,
    const float* __restrict__ bi, const float* __restrict__ bhn,
    const float* __restrict__ W_gate, const float* __restrict__ b_gate,
    const float* __restrict__ W_beta, const float* __restrict__ W_sw,
    const float* __restrict__ W_mean,
    float* __restrict__ out_h, float* __restrict__ ws_invn, float* __restrict__ ws_wstr,
    float* __restrict__ ws_bh, float* __restrict__ ws_sh, float* __restrict__ ws_meanh)
{
    __shared__ float s_h[4][256];
    __shared__ float redA[4][4], redB[4][4], redC[4][4], redD[4][4];
    const int t = threadIdx.x;
    const int r0 = blockIdx.x * 4;

    const float bir = bi[t], biz = bi[t+256], bin_ = bi[t+512];
    const float bh = bhn[t];
    const float wg = W_gate[t];
    const float wb = W_beta[t];
    const float wsw = W_sw[t];
    const int lane = t & 63, wid = t >> 6;

    float hv[4];
    #pragma unroll
    for (int r=0;r<4;r++){
        const size_t gb = (size_t)(r0+r)*1024;
        float gr = g[gb + t];
        float gz = g[gb + 256 + t];
        float gni = g[gb + 512 + t];
        float gnh = g[gb + 768 + t];
        float hp = h_prev[(size_t)(r0+r)*Hdim + t];
        float rr = sigm(gr + bir);
        float zz = sigm(gz + biz);
        float nn = tanhf(gni + bin_ + rr*(gnh + bh));
        hv[r] = (1.0f - zz)*nn + zz*hp;
        s_h[r][t] = hv[r];
    }

    #pragma unroll
    for (int r=0;r<4;r++){
        float a = hv[r]*hv[r];
        float b2 = hv[r]*wg;
        float c2 = hv[r]*wb;
        float d2 = hv[r]*wsw;
        #pragma unroll
        for (int off=32; off>=1; off>>=1){
            a  += __shfl_down(a, off);
            b2 += __shfl_down(b2, off);
            c2 += __shfl_down(c2, off);
            d2 += __shfl_down(d2, off);
        }
        if (lane==0){ redA[r][wid]=a; redB[r][wid]=b2; redC[r][wid]=c2; redD[r][wid]=d2; }
    }
    __syncthreads();
    if (t < 4){
        float ss = redA[t][0]+redA[t][1]+redA[t][2]+redA[t][3];
        float gd = redB[t][0]+redB[t][1]+redB[t][2]+redB[t][3];
        float cb = redC[t][0]+redC[t][1]+redC[t][2]+redC[t][3];
        float cs = redD[t][0]+redD[t][1]+redD[t][2]+redD[t][3];
        ws_invn[r0+t] = 1.0f/(sqrtf(ss) + 1e-6f);
        ws_wstr[r0+t] = sigm(gd + b_gate[0]);
        ws_bh[r0+t] = cb;
        ws_sh[r0+t] = cs;
    }
    #pragma unroll
    for (int r=0;r<4;r++)
        out_h[(size_t)(r0+r)*Hdim + t] = hv[r];
    __syncthreads();

    // mean_h = h @ W_mean[0:256,:]  thread = 4 cols (float4) x row x K-half
    {
        const int c4 = (t & 31) << 2;
        const int row = (t >> 6);
        const int kh  = (t >> 5) & 1;
        float acc[4] = {0,0,0,0};
        const float* Wm = W_mean + (size_t)kh*128*Udim + c4;
        const float* hr = s_h[row] + kh*128;
        #pragma unroll 8
        for (int i=0;i<128;i++){
            float4 w4 = *(const float4*)(Wm + (size_t)i*Udim);
            float x = hr[i];
            acc[0] = fmaf(x, w4.x, acc[0]);
            acc[1] = fmaf(x, w4.y, acc[1]);
            acc[2] = fmaf(x, w4.z, acc[2]);
            acc[3] = fmaf(x, w4.w, acc[3]);
        }
        __syncthreads();
        s_h[row][kh*128 + c4 + 0] = acc[0];
        s_h[row][kh*128 + c4 + 1] = acc[1];
        s_h[row][kh*128 + c4 + 2] = acc[2];
        s_h[row][kh*128 + c4 + 3] = acc[3];
        __syncthreads();
        const int row2 = t >> 6;
        const int c2 = (t & 63) << 1;
        #pragma unroll
        for (int j=0;j<2;j++){
            int c = c2 + j;
            ws_meanh[(size_t)(r0+row2)*Udim + c] = s_h[row2][c] + s_h[row2][128 + c];
        }
    }
}

// ---------------- Kernel BC (R13 exact): nt loads + plain stores + fused halved epilogue ------
__global__ __launch_bounds__(256) void kBC(
    const float* __restrict__ keys, const float* __restrict__ vals,
    const float* __restrict__ age, const float* __restrict__ strength,
    const float* __restrict__ h_t,
    const float* __restrict__ ws_invn, const float* __restrict__ ws_wstr,
    const float* __restrict__ ws_bh, const float* __restrict__ ws_sh,
    const float* __restrict__ ws_meanh,
    const float* __restrict__ u_int_prev, const int* __restrict__ step_in_macro,
    const float* __restrict__ W_mean, const float* __restrict__ b_mean,
    const float* __restrict__ W_beta, const float* __restrict__ b_beta,
    const float* __restrict__ W_sw, const float* __restrict__ b_sw,
    float* __restrict__ keys_new, float* __restrict__ vals_new,
    float* __restrict__ age_new, float* __restrict__ str_new,
    float* __restrict__ out_uprop, float* __restrict__ out_switch,
    float* __restrict__ out_uint, float* __restrict__ out_beta, float* __restrict__ out_swp)
{
    __shared__ float s_sim[KS], s_wr[KS], s_rate[KS];
    __shared__ float4 s_ro[4][64];
    __shared__ float s_rov[256];
    __shared__ float s_part[2][128];
    __shared__ float s_red[2][4];
    __shared__ float s_beff;

    const int b = blockIdx.x;
    const int t = threadIdx.x, lane = t & 63, wid = t >> 6;

    float ag = 0.f, st = 0.f, wstr = 0.f;
    if (t < KS){
        ag = age[b*KS+t];
        st = strength[b*KS+t];
        wstr = ws_wstr[b];
    }

    const float invn = ws_invn[b];
    const float4 h4 = ((const float4*)(h_t + (size_t)b*Hdim))[lane];
    const float4 q4 = make_float4(h4.x*invn, h4.y*invn, h4.z*invn, h4.w*invn);

    const float* Kb = keys + (size_t)b*KS*Hdim;
    const float* Vb = vals + (size_t)b*KS*Hdim;
    float4 kreg[8], vreg[8];
    float v[16];
    #pragma unroll
    for (int s=0;s<8;s++){
        const int k = wid*8 + s;
        kreg[s] = ntload4(Kb + k*Hdim + lane*4);
        vreg[s] = ntload4(Vb + k*Hdim + lane*4);
        v[2*s]   = kreg[s].x*q4.x + kreg[s].y*q4.y + kreg[s].z*q4.z + kreg[s].w*q4.w;
        v[2*s+1] = kreg[s].x*kreg[s].x + kreg[s].y*kreg[s].y + kreg[s].z*kreg[s].z + kreg[s].w*kreg[s].w;
    }

    // ---- reduce-scatter butterfly over 64 lanes (16 partials) ----
    {
        const bool hb5 = (lane & 32) != 0;
        #pragma unroll
        for (int i=0;i<8;i++){
            float send = hb5 ? v[i] : v[i+8];
            float recv = __shfl_xor(send, 32);
            v[i] = (hb5 ? v[i+8] : v[i]) + recv;
        }
        const bool hb4 = (lane & 16) != 0;
        #pragma unroll
        for (int i=0;i<4;i++){
            float send = hb4 ? v[i] : v[i+4];
            float recv = __shfl_xor(send, 16);
            v[i] = (hb4 ? v[i+4] : v[i]) + recv;
        }
        const bool hb3 = (lane & 8) != 0;
        #pragma unroll
        for (int i=0;i<2;i++){
            float send = hb3 ? v[i] : v[i+2];
            float recv = __shfl_xor(send, 8);
            v[i] = (hb3 ? v[i+2] : v[i]) + recv;
        }
        const bool hb2 = (lane & 4) != 0;
        {
            float send = hb2 ? v[0] : v[1];
            float recv = __shfl_xor(send, 4);
            v[0] = (hb2 ? v[1] : v[0]) + recv;
        }
        float r0 = v[0];
        r0 += __shfl_xor(r0, 2);
        r0 += __shfl_xor(r0, 1);
        float other = __shfl_xor(r0, 4);
        if ((lane & 7) == 0){
            s_sim[wid*8 + (lane>>3)] = r0 / (sqrtf(other) + 1e-6f);
        }
    }
    __syncthreads();

    // ---- softmax + argmax on lanes 0..31 of wave 0 ----
    if (t < KS){
        float sim = s_sim[t];
        float cl = fminf(fmaxf(st, 0.001f), 1.0f);
        float logit = sim + 0.5f*logf(cl) - 0.02f*ag;
        float wl = 50.0f*sim + 0.05f*log1pf(ag) - 0.5f*st;

        float lmax = logit;
        #pragma unroll
        for (int off=16; off>=1; off>>=1)
            lmax = fmaxf(lmax, __shfl_xor(lmax, off));
        float e = __expf(logit - lmax);
        float es = e;
        #pragma unroll
        for (int off=16; off>=1; off>>=1)
            es += __shfl_xor(es, off);

        float wm = wl; int ki = t;
        #pragma unroll
        for (int off=16; off>=1; off>>=1){
            float ow = __shfl_xor(wm, off);
            int   ok = __shfl_xor(ki, off);
            if (ow > wm || (ow == wm && ok < ki)){ wm = ow; ki = ok; }
        }

        s_wr[t] = e / es;
        float hard = (t == ki) ? 1.0f : 0.0f;
        s_rate[t] = hard * 0.5f * wstr;
        age_new[b*KS+t] = (ag + 1.0f)*(1.0f - hard);
        float sd = st*0.995f;
        float sn = sd + hard*wstr*(1.0f - sd);
        str_new[b*KS+t] = fminf(fmaxf(sn,0.f),1.f);
    }
    __syncthreads();

    // ---- streaming update + read_out (plain cached stores) ----
    float4 ro = make_float4(0.f,0.f,0.f,0.f);
    float* KNb = keys_new + (size_t)b*KS*Hdim;
    float* VNb = vals_new + (size_t)b*KS*Hdim;
    #pragma unroll
    for (int s=0;s<8;s++){
        const int k = wid*8 + s;
        const float wr = s_wr[k];
        const float rate = s_rate[k];
        const float om = 1.0f - rate;
        ro.x = fmaf(wr, vreg[s].x, ro.x);
        ro.y = fmaf(wr, vreg[s].y, ro.y);
        ro.z = fmaf(wr, vreg[s].z, ro.z);
        ro.w = fmaf(wr, vreg[s].w, ro.w);
        float4 kn, vn;
        kn.x = om*kreg[s].x + rate*q4.x;
        kn.y = om*kreg[s].y + rate*q4.y;
        kn.z = om*kreg[s].z + rate*q4.z;
        kn.w = om*kreg[s].w + rate*q4.w;
        vn.x = om*vreg[s].x + rate*h4.x;
        vn.y = om*vreg[s].y + rate*h4.y;
        vn.z = om*vreg[s].z + rate*h4.z;
        vn.w = om*vreg[s].w + rate*h4.w;
        *(float4*)(KNb + k*Hdim + lane*4) = kn;
        *(float4*)(VNb + k*Hdim + lane*4) = vn;
    }
    s_ro[wid][lane] = ro;
    __syncthreads();
    if (t < 64){
        float4 a = s_ro[0][t], bb = s_ro[1][t], c = s_ro[2][t], d = s_ro[3][t];
        s_rov[t*4+0] = a.x+bb.x+c.x+d.x;
        s_rov[t*4+1] = a.y+bb.y+c.y+d.y;
        s_rov[t*4+2] = a.z+bb.z+c.z+d.z;
        s_rov[t*4+3] = a.w+bb.w+c.w+d.w;
    }
    __syncthreads();

    // ---- halved kC epilogue ----
    {
        const int col = t & 127;
        const int kh  = t >> 7;
        const float* rop = s_rov + kh*128;
        const float* Wm = W_mean + (size_t)(256 + kh*128)*Udim + col;
        float acc = 0.f;
        #pragma unroll 8
        for (int i=0;i<128;i++)
            acc = fmaf(rop[i], Wm[(size_t)i*Udim], acc);
        s_part[kh][col] = acc;

        float cb = s_rov[t]*W_beta[256+t];
        float cs = s_rov[t]*W_sw[256+t];
        #pragma unroll
        for (int off=32; off>=1; off>>=1){
            cb += __shfl_down(cb, off);
            cs += __shfl_down(cs, off);
        }
        if (lane == 0){ s_red[0][wid] = cb; s_red[1][wid] = cs; }
    }
    __syncthreads();
    if (t == 0){
        float db  = s_red[0][0]+s_red[0][1]+s_red[0][2]+s_red[0][3] + ws_bh[b] + b_beta[0];
        float dsw = s_red[1][0]+s_red[1][1]+s_red[1][2]+s_red[1][3] + ws_sh[b] + b_sw[0];
        float beta = 0.05f + 0.945f*sigm(db);
        float swp = sigm(dsw);
        float swf = (swp > 0.5f) ? 1.0f : 0.0f;
        if (step_in_macro[b] == 0) swf = 1.0f;
        out_beta[b]  = beta;
        out_swp[b]   = swp;
        out_switch[b]= swf;
        s_beff = beta*(1.0f - swf);
    }
    __syncthreads();
    if (t < 128){
        float mean = ws_meanh[(size_t)b*Udim + t] + s_part[0][t] + s_part[1][t] + b_mean[t];
        size_t o = (size_t)b*Udim + t;
        out_uprop[o] = mean;
        float be = s_beff;
        out_uint[o] = be*u_int_prev[o] + (1.0f-be)*mean;
    }
}

extern "C" void kernel_launch(void* const* d_in, const int* in_sizes, int n_in,
                              void* d_out, int out_size, void* d_ws, size_t ws_size,
                              hipStream_t stream)
{
    const float* h_prev   = (const float*)d_in[0];
    const float* keys     = (const float*)d_in[1];
    const float* vals     = (const float*)d_in[2];
    const float* age      = (const float*)d_in[3];
    const float* strength = (const float*)d_in[4];
    const float* obs      = (const float*)d_in[5];
    const float* ssum     = (const float*)d_in[6];
    const float* u_int_prev = (const float*)d_in[7];
    const int*   step     = (const int*)d_in[8];
    const float* W_obs    = (const float*)d_in[9];
    const float* b_obs    = (const float*)d_in[10];
    const float* W_ssum   = (const float*)d_in[11];
    const float* b_ssum   = (const float*)d_in[12];
    const float* Wi       = (const float*)d_in[13];
    const float* bi       = (const float*)d_in[14];
    const float* Wh       = (const float*)d_in[15];
    const float* bhn      = (const float*)d_in[16];
    const float* W_gate   = (const float*)d_in[17];
    const float* b_gate   = (const float*)d_in[18];
    const float* W_mean   = (const float*)d_in[19];
    const float* b_mean   = (const float*)d_in[20];
    const float* W_beta   = (const float*)d_in[22];
    const float* b_beta   = (const float*)d_in[23];
    const float* W_sw     = (const float*)d_in[24];
    const float* b_sw     = (const float*)d_in[25];

    float* out = (float*)d_out;
    float* out_h    = out;                       // 2048*256
    float* out_kn   = out_h   + 524288;          // 2048*32*256
    float* out_vn   = out_kn  + 16777216;
    float* out_age  = out_vn  + 16777216;        // 2048*32
    float* out_str  = out_age + 65536;
    float* out_up   = out_str + 65536;           // 2048*128
    float* out_sw   = out_up  + 262144;          // 2048
    float* out_ui   = out_sw  + 2048;            // 2048*128
    float* out_beta = out_ui  + 262144;          // 2048
    float* out_swp  = out_beta+ 2048;            // 2048

    float* ws = (float*)d_ws;
    float* ws_invn  = ws;                        // B
    float* ws_wstr  = ws + Bdim;                 // B
    float* ws_bh    = ws + 2*Bdim;               // B
    float* ws_sh    = ws + 3*Bdim;               // B
    float* ws_meanh = ws + 4*Bdim;               // B*128

    // scratch reusing output regions (consumed before kBC overwrites them)
    float* ws_xin = out_vn;                      // B*256 floats, overwritten by kBC later
    float* ws_g   = out_kn;                      // B*1024 floats, overwritten by kBC later

    kA1<<<Bdim/4, 256, 0, stream>>>(obs, ssum, W_obs, b_obs, W_ssum, b_ssum, ws_xin);
    kG2<<<512, 256, 0, stream>>>(ws_xin, h_prev, Wi, Wh, ws_g);
    kA3<<<Bdim/4, 256, 0, stream>>>(ws_g, h_prev, bi, bhn, W_gate, b_gate,
                                    W_beta, W_sw, W_mean,
                                    out_h, ws_invn, ws_wstr, ws_bh, ws_sh, ws_meanh);
    kBC<<<Bdim, 256, 0, stream>>>(keys, vals, age, strength, out_h,
                                  ws_invn, ws_wstr, ws_bh, ws_sh, ws_meanh,
                                  u_int_prev, step, W_mean, b_mean,
                                  W_beta, b_beta, W_sw, b_sw,
                                  out_kn, out_vn, out_age, out_str,
                                  out_up, out_sw, out_ui, out_beta, out_swp);
}

// Round 17
// 109.503 us; speedup vs baseline: 1.1536x; 1.1536x over previous
//
#include <hip/hip_runtime.h>
#include <math.h>

#define Bdim 2048
#define Hdim 256
#define KS 32
#define Udim 128
#define OBSD 128
#define PROJD 128
#define H3 768

__device__ __forceinline__ float sigm(float x){ return 1.0f/(1.0f+__expf(-x)); }

typedef float __attribute__((ext_vector_type(4))) f32x4;

__device__ __forceinline__ float4 ntload4(const float* p){
    f32x4 v = __builtin_nontemporal_load((const f32x4*)p);
    return make_float4(v.x, v.y, v.z, v.w);
}

// ---------------- Kernel A1 (R15 exact): 4 rows/block, 512 blocks ----------------
__global__ __launch_bounds__(256) void kA1(
    const float* __restrict__ obs, const float* __restrict__ ssum,
    const float* __restrict__ W_obs, const float* __restrict__ b_obs,
    const float* __restrict__ W_ssum, const float* __restrict__ b_ssum,
    float* __restrict__ xin)
{
    __shared__ float s_in[2][4][128];
    const int t = threadIdx.x;
    const int r0 = blockIdx.x * 4;

    {
        int src = t >> 7, r = (t >> 5) & 3, c4 = (t & 31) << 2;
        const float* base = src ? ssum : obs;
        float4 v = *(const float4*)(base + (size_t)(r0+r)*OBSD + c4);
        s_in[src][r][c4+0]=v.x; s_in[src][r][c4+1]=v.y;
        s_in[src][r][c4+2]=v.z; s_in[src][r][c4+3]=v.w;
    }
    __syncthreads();

    const int col = t & 127;
    const int src = t >> 7;
    const float* Wp = src ? W_ssum : W_obs;
    const float bb = src ? b_ssum[col] : b_obs[col];

    float acc[4] = {0,0,0,0};
    for (int i=0;i<128;i++){
        float w = Wp[i*PROJD + col];
        #pragma unroll
        for (int r=0;r<4;r++) acc[r] = fmaf(s_in[src][r][i], w, acc[r]);
    }
    #pragma unroll
    for (int r=0;r<4;r++)
        xin[(size_t)(r0+r)*256 + t] = tanhf(acc[r] + bb);
}

// ---------------- Kernel G2 (R5/R15 exact): 64x64 tiles, 256 thr, 512 blocks, K-chunk 16 ------
__global__ __launch_bounds__(256) void kG2(
    const float* __restrict__ xin, const float* __restrict__ hp,
    const float* __restrict__ Wi, const float* __restrict__ Wh,
    float* __restrict__ g)
{
    __shared__ float Xt[2][16][68];
    __shared__ float Wt[2][16][64];

    const int t = threadIdx.x;
    const int bx = blockIdx.x >> 4;
    const int by = blockIdx.x & 15;
    const int r0 = bx * 64;
    const int c0 = by * 64;

    const int kbeg = (c0 >= 768) ? 256 : 0;
    const int kend = (c0 >= 512 && c0 < 768) ? 256 : 512;
    const int nck  = (kend - kbeg) >> 4;

    const int sr  = t >> 2;
    const int sk4 = (t & 3) << 2;
    const size_t xbase = (size_t)(r0 + sr) * 256 + sk4;
    const int wk  = t >> 4;
    const int wc4 = (t & 15) << 2;
    const int cW  = (c0 < 512) ? c0 : (c0 - 256);

    const int rowA = (t & 15) << 2;
    const int colA = (t >> 4) << 2;

    float acc[4][4] = {{0.f}};
    float4 xr, wr;

    {
        const int k0 = kbeg;
        const float* xs = (k0 < 256) ? (xin + xbase + k0) : (hp + xbase + (k0 - 256));
        xr = *(const float4*)xs;
        const int k = k0 + wk;
        const float* wsrc = (k < 256) ? (Wi + (size_t)k*H3 + c0 + wc4)
                                      : (Wh + (size_t)(k-256)*H3 + cW + wc4);
        wr = *(const float4*)wsrc;
    }
    Xt[0][sk4+0][sr] = xr.x; Xt[0][sk4+1][sr] = xr.y;
    Xt[0][sk4+2][sr] = xr.z; Xt[0][sk4+3][sr] = xr.w;
    *(float4*)&Wt[0][wk][wc4] = wr;
    __syncthreads();

    for (int ck = 0; ck < nck; ck++){
        const int cur = ck & 1;
        const bool more = (ck + 1 < nck);
        if (more){
            const int k0 = kbeg + ((ck + 1) << 4);
            const float* xs = (k0 < 256) ? (xin + xbase + k0) : (hp + xbase + (k0 - 256));
            xr = *(const float4*)xs;
            const int k = k0 + wk;
            const float* wsrc = (k < 256) ? (Wi + (size_t)k*H3 + c0 + wc4)
                                          : (Wh + (size_t)(k-256)*H3 + cW + wc4);
            wr = *(const float4*)wsrc;
        }
        #pragma unroll
        for (int kk = 0; kk < 16; kk++){
            float4 a4 = *(const float4*)&Xt[cur][kk][rowA];
            float4 b4 = *(const float4*)&Wt[cur][kk][colA];
            float av[4] = {a4.x, a4.y, a4.z, a4.w};
            float bv[4] = {b4.x, b4.y, b4.z, b4.w};
            #pragma unroll
            for (int i=0;i<4;i++)
                #pragma unroll
                for (int j=0;j<4;j++)
                    acc[i][j] = fmaf(av[i], bv[j], acc[i][j]);
        }
        if (more){
            const int nxt = cur ^ 1;
            Xt[nxt][sk4+0][sr] = xr.x; Xt[nxt][sk4+1][sr] = xr.y;
            Xt[nxt][sk4+2][sr] = xr.z; Xt[nxt][sk4+3][sr] = xr.w;
            *(float4*)&Wt[nxt][wk][wc4] = wr;
            __syncthreads();
        }
    }

    #pragma unroll
    for (int i=0;i<4;i++){
        float4 o = make_float4(acc[i][0], acc[i][1], acc[i][2], acc[i][3]);
        *(float4*)&g[(size_t)(r0 + rowA + i)*1024 + c0 + colA] = o;
    }
}

// ---------------- Kernel A3 (R12/R15 exact): 4 rows/block, float4 W_mean GEMV ----------------
__global__ __launch_bounds__(256) void kA3(
    const float* __restrict__ g, const float* __restrict__ h_prev,
    const float* __restrict__ bi, const float* __restrict__ bhn,
    const float* __restrict__ W_gate, const float* __restrict__ b_gate,
    const float* __restrict__ W_beta, const float* __restrict__ W_sw,
    const float* __restrict__ W_mean,
    float* __restrict__ out_h, float* __restrict__ ws_invn, float* __restrict__ ws_wstr,
    float* __restrict__ ws_bh, float* __restrict__ ws_sh, float* __restrict__ ws_meanh)
{
    __shared__ float s_h[4][256];
    __shared__ float redA[4][4], redB[4][4], redC[4][4], redD[4][4];
    const int t = threadIdx.x;
    const int r0 = blockIdx.x * 4;

    const float bir = bi[t], biz = bi[t+256], bin_ = bi[t+512];
    const float bh = bhn[t];
    const float wg = W_gate[t];
    const float wb = W_beta[t];
    const float wsw = W_sw[t];
    const int lane = t & 63, wid = t >> 6;

    float hv[4];
    #pragma unroll
    for (int r=0;r<4;r++){
        const size_t gb = (size_t)(r0+r)*1024;
        float gr = g[gb + t];
        float gz = g[gb + 256 + t];
        float gni = g[gb + 512 + t];
        float gnh = g[gb + 768 + t];
        float hp = h_prev[(size_t)(r0+r)*Hdim + t];
        float rr = sigm(gr + bir);
        float zz = sigm(gz + biz);
        float nn = tanhf(gni + bin_ + rr*(gnh + bh));
        hv[r] = (1.0f - zz)*nn + zz*hp;
        s_h[r][t] = hv[r];
    }

    #pragma unroll
    for (int r=0;r<4;r++){
        float a = hv[r]*hv[r];
        float b2 = hv[r]*wg;
        float c2 = hv[r]*wb;
        float d2 = hv[r]*wsw;
        #pragma unroll
        for (int off=32; off>=1; off>>=1){
            a  += __shfl_down(a, off);
            b2 += __shfl_down(b2, off);
            c2 += __shfl_down(c2, off);
            d2 += __shfl_down(d2, off);
        }
        if (lane==0){ redA[r][wid]=a; redB[r][wid]=b2; redC[r][wid]=c2; redD[r][wid]=d2; }
    }
    __syncthreads();
    if (t < 4){
        float ss = redA[t][0]+redA[t][1]+redA[t][2]+redA[t][3];
        float gd = redB[t][0]+redB[t][1]+redB[t][2]+redB[t][3];
        float cb = redC[t][0]+redC[t][1]+redC[t][2]+redC[t][3];
        float cs = redD[t][0]+redD[t][1]+redD[t][2]+redD[t][3];
        ws_invn[r0+t] = 1.0f/(sqrtf(ss) + 1e-6f);
        ws_wstr[r0+t] = sigm(gd + b_gate[0]);
        ws_bh[r0+t] = cb;
        ws_sh[r0+t] = cs;
    }
    #pragma unroll
    for (int r=0;r<4;r++)
        out_h[(size_t)(r0+r)*Hdim + t] = hv[r];
    __syncthreads();

    // mean_h = h @ W_mean[0:256,:]  thread = 4 cols (float4) x row x K-half
    {
        const int c4 = (t & 31) << 2;
        const int row = (t >> 6);
        const int kh  = (t >> 5) & 1;
        float acc[4] = {0,0,0,0};
        const float* Wm = W_mean + (size_t)kh*128*Udim + c4;
        const float* hr = s_h[row] + kh*128;
        #pragma unroll 8
        for (int i=0;i<128;i++){
            float4 w4 = *(const float4*)(Wm + (size_t)i*Udim);
            float x = hr[i];
            acc[0] = fmaf(x, w4.x, acc[0]);
            acc[1] = fmaf(x, w4.y, acc[1]);
            acc[2] = fmaf(x, w4.z, acc[2]);
            acc[3] = fmaf(x, w4.w, acc[3]);
        }
        __syncthreads();
        s_h[row][kh*128 + c4 + 0] = acc[0];
        s_h[row][kh*128 + c4 + 1] = acc[1];
        s_h[row][kh*128 + c4 + 2] = acc[2];
        s_h[row][kh*128 + c4 + 3] = acc[3];
        __syncthreads();
        const int row2 = t >> 6;
        const int c2 = (t & 63) << 1;
        #pragma unroll
        for (int j=0;j<2;j++){
            int c = c2 + j;
            ws_meanh[(size_t)(r0+row2)*Udim + c] = s_h[row2][c] + s_h[row2][128 + c];
        }
    }
}

// ---------------- Kernel BC (R13/R15 exact): nt loads + plain stores + fused halved epilogue --
__global__ __launch_bounds__(256) void kBC(
    const float* __restrict__ keys, const float* __restrict__ vals,
    const float* __restrict__ age, const float* __restrict__ strength,
    const float* __restrict__ h_t,
    const float* __restrict__ ws_invn, const float* __restrict__ ws_wstr,
    const float* __restrict__ ws_bh, const float* __restrict__ ws_sh,
    const float* __restrict__ ws_meanh,
    const float* __restrict__ u_int_prev, const int* __restrict__ step_in_macro,
    const float* __restrict__ W_mean, const float* __restrict__ b_mean,
    const float* __restrict__ W_beta, const float* __restrict__ b_beta,
    const float* __restrict__ W_sw, const float* __restrict__ b_sw,
    float* __restrict__ keys_new, float* __restrict__ vals_new,
    float* __restrict__ age_new, float* __restrict__ str_new,
    float* __restrict__ out_uprop, float* __restrict__ out_switch,
    float* __restrict__ out_uint, float* __restrict__ out_beta, float* __restrict__ out_swp)
{
    __shared__ float s_sim[KS], s_wr[KS], s_rate[KS];
    __shared__ float4 s_ro[4][64];
    __shared__ float s_rov[256];
    __shared__ float s_part[2][128];
    __shared__ float s_red[2][4];
    __shared__ float s_beff;

    const int b = blockIdx.x;
    const int t = threadIdx.x, lane = t & 63, wid = t >> 6;

    float ag = 0.f, st = 0.f, wstr = 0.f;
    if (t < KS){
        ag = age[b*KS+t];
        st = strength[b*KS+t];
        wstr = ws_wstr[b];
    }

    const float invn = ws_invn[b];
    const float4 h4 = ((const float4*)(h_t + (size_t)b*Hdim))[lane];
    const float4 q4 = make_float4(h4.x*invn, h4.y*invn, h4.z*invn, h4.w*invn);

    const float* Kb = keys + (size_t)b*KS*Hdim;
    const float* Vb = vals + (size_t)b*KS*Hdim;
    float4 kreg[8], vreg[8];
    float v[16];
    #pragma unroll
    for (int s=0;s<8;s++){
        const int k = wid*8 + s;
        kreg[s] = ntload4(Kb + k*Hdim + lane*4);
        vreg[s] = ntload4(Vb + k*Hdim + lane*4);
        v[2*s]   = kreg[s].x*q4.x + kreg[s].y*q4.y + kreg[s].z*q4.z + kreg[s].w*q4.w;
        v[2*s+1] = kreg[s].x*kreg[s].x + kreg[s].y*kreg[s].y + kreg[s].z*kreg[s].z + kreg[s].w*kreg[s].w;
    }

    // ---- reduce-scatter butterfly over 64 lanes (16 partials) ----
    {
        const bool hb5 = (lane & 32) != 0;
        #pragma unroll
        for (int i=0;i<8;i++){
            float send = hb5 ? v[i] : v[i+8];
            float recv = __shfl_xor(send, 32);
            v[i] = (hb5 ? v[i+8] : v[i]) + recv;
        }
        const bool hb4 = (lane & 16) != 0;
        #pragma unroll
        for (int i=0;i<4;i++){
            float send = hb4 ? v[i] : v[i+4];
            float recv = __shfl_xor(send, 16);
            v[i] = (hb4 ? v[i+4] : v[i]) + recv;
        }
        const bool hb3 = (lane & 8) != 0;
        #pragma unroll
        for (int i=0;i<2;i++){
            float send = hb3 ? v[i] : v[i+2];
            float recv = __shfl_xor(send, 8);
            v[i] = (hb3 ? v[i+2] : v[i]) + recv;
        }
        const bool hb2 = (lane & 4) != 0;
        {
            float send = hb2 ? v[0] : v[1];
            float recv = __shfl_xor(send, 4);
            v[0] = (hb2 ? v[1] : v[0]) + recv;
        }
        float r0 = v[0];
        r0 += __shfl_xor(r0, 2);
        r0 += __shfl_xor(r0, 1);
        float other = __shfl_xor(r0, 4);
        if ((lane & 7) == 0){
            s_sim[wid*8 + (lane>>3)] = r0 / (sqrtf(other) + 1e-6f);
        }
    }
    __syncthreads();

    // ---- softmax + argmax on lanes 0..31 of wave 0 ----
    if (t < KS){
        float sim = s_sim[t];
        float cl = fminf(fmaxf(st, 0.001f), 1.0f);
        float logit = sim + 0.5f*logf(cl) - 0.02f*ag;
        float wl = 50.0f*sim + 0.05f*log1pf(ag) - 0.5f*st;

        float lmax = logit;
        #pragma unroll
        for (int off=16; off>=1; off>>=1)
            lmax = fmaxf(lmax, __shfl_xor(lmax, off));
        float e = __expf(logit - lmax);
        float es = e;
        #pragma unroll
        for (int off=16; off>=1; off>>=1)
            es += __shfl_xor(es, off);

        float wm = wl; int ki = t;
        #pragma unroll
        for (int off=16; off>=1; off>>=1){
            float ow = __shfl_xor(wm, off);
            int   ok = __shfl_xor(ki, off);
            if (ow > wm || (ow == wm && ok < ki)){ wm = ow; ki = ok; }
        }

        s_wr[t] = e / es;
        float hard = (t == ki) ? 1.0f : 0.0f;
        s_rate[t] = hard * 0.5f * wstr;
        age_new[b*KS+t] = (ag + 1.0f)*(1.0f - hard);
        float sd = st*0.995f;
        float sn = sd + hard*wstr*(1.0f - sd);
        str_new[b*KS+t] = fminf(fmaxf(sn,0.f),1.f);
    }
    __syncthreads();

    // ---- streaming update + read_out (plain cached stores) ----
    float4 ro = make_float4(0.f,0.f,0.f,0.f);
    float* KNb = keys_new + (size_t)b*KS*Hdim;
    float* VNb = vals_new + (size_t)b*KS*Hdim;
    #pragma unroll
    for (int s=0;s<8;s++){
        const int k = wid*8 + s;
        const float wr = s_wr[k];
        const float rate = s_rate[k];
        const float om = 1.0f - rate;
        ro.x = fmaf(wr, vreg[s].x, ro.x);
        ro.y = fmaf(wr, vreg[s].y, ro.y);
        ro.z = fmaf(wr, vreg[s].z, ro.z);
        ro.w = fmaf(wr, vreg[s].w, ro.w);
        float4 kn, vn;
        kn.x = om*kreg[s].x + rate*q4.x;
        kn.y = om*kreg[s].y + rate*q4.y;
        kn.z = om*kreg[s].z + rate*q4.z;
        kn.w = om*kreg[s].w + rate*q4.w;
        vn.x = om*vreg[s].x + rate*h4.x;
        vn.y = om*vreg[s].y + rate*h4.y;
        vn.z = om*vreg[s].z + rate*h4.z;
        vn.w = om*vreg[s].w + rate*h4.w;
        *(float4*)(KNb + k*Hdim + lane*4) = kn;
        *(float4*)(VNb + k*Hdim + lane*4) = vn;
    }
    s_ro[wid][lane] = ro;
    __syncthreads();
    if (t < 64){
        float4 a = s_ro[0][t], bb = s_ro[1][t], c = s_ro[2][t], d = s_ro[3][t];
        s_rov[t*4+0] = a.x+bb.x+c.x+d.x;
        s_rov[t*4+1] = a.y+bb.y+c.y+d.y;
        s_rov[t*4+2] = a.z+bb.z+c.z+d.z;
        s_rov[t*4+3] = a.w+bb.w+c.w+d.w;
    }
    __syncthreads();

    // ---- halved kC epilogue ----
    {
        const int col = t & 127;
        const int kh  = t >> 7;
        const float* rop = s_rov + kh*128;
        const float* Wm = W_mean + (size_t)(256 + kh*128)*Udim + col;
        float acc = 0.f;
        #pragma unroll 8
        for (int i=0;i<128;i++)
            acc = fmaf(rop[i], Wm[(size_t)i*Udim], acc);
        s_part[kh][col] = acc;

        float cb = s_rov[t]*W_beta[256+t];
        float cs = s_rov[t]*W_sw[256+t];
        #pragma unroll
        for (int off=32; off>=1; off>>=1){
            cb += __shfl_down(cb, off);
            cs += __shfl_down(cs, off);
        }
        if (lane == 0){ s_red[0][wid] = cb; s_red[1][wid] = cs; }
    }
    __syncthreads();
    if (t == 0){
        float db  = s_red[0][0]+s_red[0][1]+s_red[0][2]+s_red[0][3] + ws_bh[b] + b_beta[0];
        float dsw = s_red[1][0]+s_red[1][1]+s_red[1][2]+s_red[1][3] + ws_sh[b] + b_sw[0];
        float beta = 0.05f + 0.945f*sigm(db);
        float swp = sigm(dsw);
        float swf = (swp > 0.5f) ? 1.0f : 0.0f;
        if (step_in_macro[b] == 0) swf = 1.0f;
        out_beta[b]  = beta;
        out_swp[b]   = swp;
        out_switch[b]= swf;
        s_beff = beta*(1.0f - swf);
    }
    __syncthreads();
    if (t < 128){
        float mean = ws_meanh[(size_t)b*Udim + t] + s_part[0][t] + s_part[1][t] + b_mean[t];
        size_t o = (size_t)b*Udim + t;
        out_uprop[o] = mean;
        float be = s_beff;
        out_uint[o] = be*u_int_prev[o] + (1.0f-be)*mean;
    }
}

extern "C" void kernel_launch(void* const* d_in, const int* in_sizes, int n_in,
                              void* d_out, int out_size, void* d_ws, size_t ws_size,
                              hipStream_t stream)
{
    const float* h_prev   = (const float*)d_in[0];
    const float* keys     = (const float*)d_in[1];
    const float* vals     = (const float*)d_in[2];
    const float* age      = (const float*)d_in[3];
    const float* strength = (const float*)d_in[4];
    const float* obs      = (const float*)d_in[5];
    const float* ssum     = (const float*)d_in[6];
    const float* u_int_prev = (const float*)d_in[7];
    const int*   step     = (const int*)d_in[8];
    const float* W_obs    = (const float*)d_in[9];
    const float* b_obs    = (const float*)d_in[10];
    const float* W_ssum   = (const float*)d_in[11];
    const float* b_ssum   = (const float*)d_in[12];
    const float* Wi       = (const float*)d_in[13];
    const float* bi       = (const float*)d_in[14];
    const float* Wh       = (const float*)d_in[15];
    const float* bhn      = (const float*)d_in[16];
    const float* W_gate   = (const float*)d_in[17];
    const float* b_gate   = (const float*)d_in[18];
    const float* W_mean   = (const float*)d_in[19];
    const float* b_mean   = (const float*)d_in[20];
    const float* W_beta   = (const float*)d_in[22];
    const float* b_beta   = (const float*)d_in[23];
    const float* W_sw     = (const float*)d_in[24];
    const float* b_sw     = (const float*)d_in[25];

    float* out = (float*)d_out;
    float* out_h    = out;                       // 2048*256
    float* out_kn   = out_h   + 524288;          // 2048*32*256
    float* out_vn   = out_kn  + 16777216;
    float* out_age  = out_vn  + 16777216;        // 2048*32
    float* out_str  = out_age + 65536;
    float* out_up   = out_str + 65536;           // 2048*128
    float* out_sw   = out_up  + 262144;          // 2048
    float* out_ui   = out_sw  + 2048;            // 2048*128
    float* out_beta = out_ui  + 262144;          // 2048
    float* out_swp  = out_beta+ 2048;            // 2048

    float* ws = (float*)d_ws;
    float* ws_invn  = ws;                        // B
    float* ws_wstr  = ws + Bdim;                 // B
    float* ws_bh    = ws + 2*Bdim;               // B
    float* ws_sh    = ws + 3*Bdim;               // B
    float* ws_meanh = ws + 4*Bdim;               // B*128

    // scratch reusing output regions (consumed before kBC overwrites them)
    float* ws_xin = out_vn;                      // B*256 floats, overwritten by kBC later
    float* ws_g   = out_kn;                      // B*1024 floats, overwritten by kBC later

    kA1<<<Bdim/4, 256, 0, stream>>>(obs, ssum, W_obs, b_obs, W_ssum, b_ssum, ws_xin);
    kG2<<<512, 256, 0, stream>>>(ws_xin, h_prev, Wi, Wh, ws_g);
    kA3<<<Bdim/4, 256, 0, stream>>>(ws_g, h_prev, bi, bhn, W_gate, b_gate,
                                    W_beta, W_sw, W_mean,
                                    out_h, ws_invn, ws_wstr, ws_bh, ws_sh, ws_meanh);
    kBC<<<Bdim, 256, 0, stream>>>(keys, vals, age, strength, out_h,
                                  ws_invn, ws_wstr, ws_bh, ws_sh, ws_meanh,
                                  u_int_prev, step, W_mean, b_mean,
                                  W_beta, b_beta, W_sw, b_sw,
                                  out_kn, out_vn, out_age, out_str,
                                  out_up, out_sw, out_ui, out_beta, out_swp);
}

// Round 18
// 109.437 us; speedup vs baseline: 1.1543x; 1.0006x over previous
//
#include <hip/hip_runtime.h>
#include <math.h>

#define Bdim 2048
#define Hdim 256
#define KS 32
#define Udim 128
#define OBSD 128
#define PROJD 128
#define H3 768

__device__ __forceinline__ float sigm(float x){ return 1.0f/(1.0f+__expf(-x)); }

typedef float __attribute__((ext_vector_type(4))) f32x4;

__device__ __forceinline__ float4 ntload4(const float* p){
    f32x4 v = __builtin_nontemporal_load((const f32x4*)p);
    return make_float4(v.x, v.y, v.z, v.w);
}

// ---------------- Kernel A1 (R15 exact): 4 rows/block, 512 blocks ----------------
__global__ __launch_bounds__(256) void kA1(
    const float* __restrict__ obs, const float* __restrict__ ssum,
    const float* __restrict__ W_obs, const float* __restrict__ b_obs,
    const float* __restrict__ W_ssum, const float* __restrict__ b_ssum,
    float* __restrict__ xin)
{
    __shared__ float s_in[2][4][128];
    const int t = threadIdx.x;
    const int r0 = blockIdx.x * 4;

    {
        int src = t >> 7, r = (t >> 5) & 3, c4 = (t & 31) << 2;
        const float* base = src ? ssum : obs;
        float4 v = *(const float4*)(base + (size_t)(r0+r)*OBSD + c4);
        s_in[src][r][c4+0]=v.x; s_in[src][r][c4+1]=v.y;
        s_in[src][r][c4+2]=v.z; s_in[src][r][c4+3]=v.w;
    }
    __syncthreads();

    const int col = t & 127;
    const int src = t >> 7;
    const float* Wp = src ? W_ssum : W_obs;
    const float bb = src ? b_ssum[col] : b_obs[col];

    float acc[4] = {0,0,0,0};
    for (int i=0;i<128;i++){
        float w = Wp[i*PROJD + col];
        #pragma unroll
        for (int r=0;r<4;r++) acc[r] = fmaf(s_in[src][r][i], w, acc[r]);
    }
    #pragma unroll
    for (int r=0;r<4;r++)
        xin[(size_t)(r0+r)*256 + t] = tanhf(acc[r] + bb);
}

// ---------------- Kernel G2 (R5/R15 exact): 64x64 tiles, 256 thr, 512 blocks, K-chunk 16 ------
__global__ __launch_bounds__(256) void kG2(
    const float* __restrict__ xin, const float* __restrict__ hp,
    const float* __restrict__ Wi, const float* __restrict__ Wh,
    float* __restrict__ g)
{
    __shared__ float Xt[2][16][68];
    __shared__ float Wt[2][16][64];

    const int t = threadIdx.x;
    const int bx = blockIdx.x >> 4;
    const int by = blockIdx.x & 15;
    const int r0 = bx * 64;
    const int c0 = by * 64;

    const int kbeg = (c0 >= 768) ? 256 : 0;
    const int kend = (c0 >= 512 && c0 < 768) ? 256 : 512;
    const int nck  = (kend - kbeg) >> 4;

    const int sr  = t >> 2;
    const int sk4 = (t & 3) << 2;
    const size_t xbase = (size_t)(r0 + sr) * 256 + sk4;
    const int wk  = t >> 4;
    const int wc4 = (t & 15) << 2;
    const int cW  = (c0 < 512) ? c0 : (c0 - 256);

    const int rowA = (t & 15) << 2;
    const int colA = (t >> 4) << 2;

    float acc[4][4] = {{0.f}};
    float4 xr, wr;

    {
        const int k0 = kbeg;
        const float* xs = (k0 < 256) ? (xin + xbase + k0) : (hp + xbase + (k0 - 256));
        xr = *(const float4*)xs;
        const int k = k0 + wk;
        const float* wsrc = (k < 256) ? (Wi + (size_t)k*H3 + c0 + wc4)
                                      : (Wh + (size_t)(k-256)*H3 + cW + wc4);
        wr = *(const float4*)wsrc;
    }
    Xt[0][sk4+0][sr] = xr.x; Xt[0][sk4+1][sr] = xr.y;
    Xt[0][sk4+2][sr] = xr.z; Xt[0][sk4+3][sr] = xr.w;
    *(float4*)&Wt[0][wk][wc4] = wr;
    __syncthreads();

    for (int ck = 0; ck < nck; ck++){
        const int cur = ck & 1;
        const bool more = (ck + 1 < nck);
        if (more){
            const int k0 = kbeg + ((ck + 1) << 4);
            const float* xs = (k0 < 256) ? (xin + xbase + k0) : (hp + xbase + (k0 - 256));
            xr = *(const float4*)xs;
            const int k = k0 + wk;
            const float* wsrc = (k < 256) ? (Wi + (size_t)k*H3 + c0 + wc4)
                                          : (Wh + (size_t)(k-256)*H3 + cW + wc4);
            wr = *(const float4*)wsrc;
        }
        #pragma unroll
        for (int kk = 0; kk < 16; kk++){
            float4 a4 = *(const float4*)&Xt[cur][kk][rowA];
            float4 b4 = *(const float4*)&Wt[cur][kk][colA];
            float av[4] = {a4.x, a4.y, a4.z, a4.w};
            float bv[4] = {b4.x, b4.y, b4.z, b4.w};
            #pragma unroll
            for (int i=0;i<4;i++)
                #pragma unroll
                for (int j=0;j<4;j++)
                    acc[i][j] = fmaf(av[i], bv[j], acc[i][j]);
        }
        if (more){
            const int nxt = cur ^ 1;
            Xt[nxt][sk4+0][sr] = xr.x; Xt[nxt][sk4+1][sr] = xr.y;
            Xt[nxt][sk4+2][sr] = xr.z; Xt[nxt][sk4+3][sr] = xr.w;
            *(float4*)&Wt[nxt][wk][wc4] = wr;
            __syncthreads();
        }
    }

    #pragma unroll
    for (int i=0;i<4;i++){
        float4 o = make_float4(acc[i][0], acc[i][1], acc[i][2], acc[i][3]);
        *(float4*)&g[(size_t)(r0 + rowA + i)*1024 + c0 + colA] = o;
    }
}

// ---------------- Kernel A3 (R12/R15 exact): 4 rows/block, float4 W_mean GEMV ----------------
__global__ __launch_bounds__(256) void kA3(
    const float* __restrict__ g, const float* __restrict__ h_prev,
    const float* __restrict__ bi, const float* __restrict__ bhn,
    const float* __restrict__ W_gate, const float* __restrict__ b_gate,
    const float* __restrict__ W_beta, const float* __restrict__ W_sw,
    const float* __restrict__ W_mean,
    float* __restrict__ out_h, float* __restrict__ ws_invn, float* __restrict__ ws_wstr,
    float* __restrict__ ws_bh, float* __restrict__ ws_sh, float* __restrict__ ws_meanh)
{
    __shared__ float s_h[4][256];
    __shared__ float redA[4][4], redB[4][4], redC[4][4], redD[4][4];
    const int t = threadIdx.x;
    const int r0 = blockIdx.x * 4;

    const float bir = bi[t], biz = bi[t+256], bin_ = bi[t+512];
    const float bh = bhn[t];
    const float wg = W_gate[t];
    const float wb = W_beta[t];
    const float wsw = W_sw[t];
    const int lane = t & 63, wid = t >> 6;

    float hv[4];
    #pragma unroll
    for (int r=0;r<4;r++){
        const size_t gb = (size_t)(r0+r)*1024;
        float gr = g[gb + t];
        float gz = g[gb + 256 + t];
        float gni = g[gb + 512 + t];
        float gnh = g[gb + 768 + t];
        float hp = h_prev[(size_t)(r0+r)*Hdim + t];
        float rr = sigm(gr + bir);
        float zz = sigm(gz + biz);
        float nn = tanhf(gni + bin_ + rr*(gnh + bh));
        hv[r] = (1.0f - zz)*nn + zz*hp;
        s_h[r][t] = hv[r];
    }

    #pragma unroll
    for (int r=0;r<4;r++){
        float a = hv[r]*hv[r];
        float b2 = hv[r]*wg;
        float c2 = hv[r]*wb;
        float d2 = hv[r]*wsw;
        #pragma unroll
        for (int off=32; off>=1; off>>=1){
            a  += __shfl_down(a, off);
            b2 += __shfl_down(b2, off);
            c2 += __shfl_down(c2, off);
            d2 += __shfl_down(d2, off);
        }
        if (lane==0){ redA[r][wid]=a; redB[r][wid]=b2; redC[r][wid]=c2; redD[r][wid]=d2; }
    }
    __syncthreads();
    if (t < 4){
        float ss = redA[t][0]+redA[t][1]+redA[t][2]+redA[t][3];
        float gd = redB[t][0]+redB[t][1]+redB[t][2]+redB[t][3];
        float cb = redC[t][0]+redC[t][1]+redC[t][2]+redC[t][3];
        float cs = redD[t][0]+redD[t][1]+redD[t][2]+redD[t][3];
        ws_invn[r0+t] = 1.0f/(sqrtf(ss) + 1e-6f);
        ws_wstr[r0+t] = sigm(gd + b_gate[0]);
        ws_bh[r0+t] = cb;
        ws_sh[r0+t] = cs;
    }
    #pragma unroll
    for (int r=0;r<4;r++)
        out_h[(size_t)(r0+r)*Hdim + t] = hv[r];
    __syncthreads();

    // mean_h = h @ W_mean[0:256,:]  thread = 4 cols (float4) x row x K-half
    {
        const int c4 = (t & 31) << 2;
        const int row = (t >> 6);
        const int kh  = (t >> 5) & 1;
        float acc[4] = {0,0,0,0};
        const float* Wm = W_mean + (size_t)kh*128*Udim + c4;
        const float* hr = s_h[row] + kh*128;
        #pragma unroll 8
        for (int i=0;i<128;i++){
            float4 w4 = *(const float4*)(Wm + (size_t)i*Udim);
            float x = hr[i];
            acc[0] = fmaf(x, w4.x, acc[0]);
            acc[1] = fmaf(x, w4.y, acc[1]);
            acc[2] = fmaf(x, w4.z, acc[2]);
            acc[3] = fmaf(x, w4.w, acc[3]);
        }
        __syncthreads();
        s_h[row][kh*128 + c4 + 0] = acc[0];
        s_h[row][kh*128 + c4 + 1] = acc[1];
        s_h[row][kh*128 + c4 + 2] = acc[2];
        s_h[row][kh*128 + c4 + 3] = acc[3];
        __syncthreads();
        const int row2 = t >> 6;
        const int c2 = (t & 63) << 1;
        #pragma unroll
        for (int j=0;j<2;j++){
            int c = c2 + j;
            ws_meanh[(size_t)(r0+row2)*Udim + c] = s_h[row2][c] + s_h[row2][128 + c];
        }
    }
}

// ---------------- Kernel BC (R13/R15 exact): nt loads + plain stores + fused halved epilogue --
__global__ __launch_bounds__(256) void kBC(
    const float* __restrict__ keys, const float* __restrict__ vals,
    const float* __restrict__ age, const float* __restrict__ strength,
    const float* __restrict__ h_t,
    const float* __restrict__ ws_invn, const float* __restrict__ ws_wstr,
    const float* __restrict__ ws_bh, const float* __restrict__ ws_sh,
    const float* __restrict__ ws_meanh,
    const float* __restrict__ u_int_prev, const int* __restrict__ step_in_macro,
    const float* __restrict__ W_mean, const float* __restrict__ b_mean,
    const float* __restrict__ W_beta, const float* __restrict__ b_beta,
    const float* __restrict__ W_sw, const float* __restrict__ b_sw,
    float* __restrict__ keys_new, float* __restrict__ vals_new,
    float* __restrict__ age_new, float* __restrict__ str_new,
    float* __restrict__ out_uprop, float* __restrict__ out_switch,
    float* __restrict__ out_uint, float* __restrict__ out_beta, float* __restrict__ out_swp)
{
    __shared__ float s_sim[KS], s_wr[KS], s_rate[KS];
    __shared__ float4 s_ro[4][64];
    __shared__ float s_rov[256];
    __shared__ float s_part[2][128];
    __shared__ float s_red[2][4];
    __shared__ float s_beff;

    const int b = blockIdx.x;
    const int t = threadIdx.x, lane = t & 63, wid = t >> 6;

    float ag = 0.f, st = 0.f, wstr = 0.f;
    if (t < KS){
        ag = age[b*KS+t];
        st = strength[b*KS+t];
        wstr = ws_wstr[b];
    }

    const float invn = ws_invn[b];
    const float4 h4 = ((const float4*)(h_t + (size_t)b*Hdim))[lane];
    const float4 q4 = make_float4(h4.x*invn, h4.y*invn, h4.z*invn, h4.w*invn);

    const float* Kb = keys + (size_t)b*KS*Hdim;
    const float* Vb = vals + (size_t)b*KS*Hdim;
    float4 kreg[8], vreg[8];
    float v[16];
    #pragma unroll
    for (int s=0;s<8;s++){
        const int k = wid*8 + s;
        kreg[s] = ntload4(Kb + k*Hdim + lane*4);
        vreg[s] = ntload4(Vb + k*Hdim + lane*4);
        v[2*s]   = kreg[s].x*q4.x + kreg[s].y*q4.y + kreg[s].z*q4.z + kreg[s].w*q4.w;
        v[2*s+1] = kreg[s].x*kreg[s].x + kreg[s].y*kreg[s].y + kreg[s].z*kreg[s].z + kreg[s].w*kreg[s].w;
    }

    // ---- reduce-scatter butterfly over 64 lanes (16 partials) ----
    {
        const bool hb5 = (lane & 32) != 0;
        #pragma unroll
        for (int i=0;i<8;i++){
            float send = hb5 ? v[i] : v[i+8];
            float recv = __shfl_xor(send, 32);
            v[i] = (hb5 ? v[i+8] : v[i]) + recv;
        }
        const bool hb4 = (lane & 16) != 0;
        #pragma unroll
        for (int i=0;i<4;i++){
            float send = hb4 ? v[i] : v[i+4];
            float recv = __shfl_xor(send, 16);
            v[i] = (hb4 ? v[i+4] : v[i]) + recv;
        }
        const bool hb3 = (lane & 8) != 0;
        #pragma unroll
        for (int i=0;i<2;i++){
            float send = hb3 ? v[i] : v[i+2];
            float recv = __shfl_xor(send, 8);
            v[i] = (hb3 ? v[i+2] : v[i]) + recv;
        }
        const bool hb2 = (lane & 4) != 0;
        {
            float send = hb2 ? v[0] : v[1];
            float recv = __shfl_xor(send, 4);
            v[0] = (hb2 ? v[1] : v[0]) + recv;
        }
        float r0 = v[0];
        r0 += __shfl_xor(r0, 2);
        r0 += __shfl_xor(r0, 1);
        float other = __shfl_xor(r0, 4);
        if ((lane & 7) == 0){
            s_sim[wid*8 + (lane>>3)] = r0 / (sqrtf(other) + 1e-6f);
        }
    }
    __syncthreads();

    // ---- softmax + argmax on lanes 0..31 of wave 0 ----
    if (t < KS){
        float sim = s_sim[t];
        float cl = fminf(fmaxf(st, 0.001f), 1.0f);
        float logit = sim + 0.5f*logf(cl) - 0.02f*ag;
        float wl = 50.0f*sim + 0.05f*log1pf(ag) - 0.5f*st;

        float lmax = logit;
        #pragma unroll
        for (int off=16; off>=1; off>>=1)
            lmax = fmaxf(lmax, __shfl_xor(lmax, off));
        float e = __expf(logit - lmax);
        float es = e;
        #pragma unroll
        for (int off=16; off>=1; off>>=1)
            es += __shfl_xor(es, off);

        float wm = wl; int ki = t;
        #pragma unroll
        for (int off=16; off>=1; off>>=1){
            float ow = __shfl_xor(wm, off);
            int   ok = __shfl_xor(ki, off);
            if (ow > wm || (ow == wm && ok < ki)){ wm = ow; ki = ok; }
        }

        s_wr[t] = e / es;
        float hard = (t == ki) ? 1.0f : 0.0f;
        s_rate[t] = hard * 0.5f * wstr;
        age_new[b*KS+t] = (ag + 1.0f)*(1.0f - hard);
        float sd = st*0.995f;
        float sn = sd + hard*wstr*(1.0f - sd);
        str_new[b*KS+t] = fminf(fmaxf(sn,0.f),1.f);
    }
    __syncthreads();

    // ---- streaming update + read_out (plain cached stores) ----
    float4 ro = make_float4(0.f,0.f,0.f,0.f);
    float* KNb = keys_new + (size_t)b*KS*Hdim;
    float* VNb = vals_new + (size_t)b*KS*Hdim;
    #pragma unroll
    for (int s=0;s<8;s++){
        const int k = wid*8 + s;
        const float wr = s_wr[k];
        const float rate = s_rate[k];
        const float om = 1.0f - rate;
        ro.x = fmaf(wr, vreg[s].x, ro.x);
        ro.y = fmaf(wr, vreg[s].y, ro.y);
        ro.z = fmaf(wr, vreg[s].z, ro.z);
        ro.w = fmaf(wr, vreg[s].w, ro.w);
        float4 kn, vn;
        kn.x = om*kreg[s].x + rate*q4.x;
        kn.y = om*kreg[s].y + rate*q4.y;
        kn.z = om*kreg[s].z + rate*q4.z;
        kn.w = om*kreg[s].w + rate*q4.w;
        vn.x = om*vreg[s].x + rate*h4.x;
        vn.y = om*vreg[s].y + rate*h4.y;
        vn.z = om*vreg[s].z + rate*h4.z;
        vn.w = om*vreg[s].w + rate*h4.w;
        *(float4*)(KNb + k*Hdim + lane*4) = kn;
        *(float4*)(VNb + k*Hdim + lane*4) = vn;
    }
    s_ro[wid][lane] = ro;
    __syncthreads();
    if (t < 64){
        float4 a = s_ro[0][t], bb = s_ro[1][t], c = s_ro[2][t], d = s_ro[3][t];
        s_rov[t*4+0] = a.x+bb.x+c.x+d.x;
        s_rov[t*4+1] = a.y+bb.y+c.y+d.y;
        s_rov[t*4+2] = a.z+bb.z+c.z+d.z;
        s_rov[t*4+3] = a.w+bb.w+c.w+d.w;
    }
    __syncthreads();

    // ---- halved kC epilogue ----
    {
        const int col = t & 127;
        const int kh  = t >> 7;
        const float* rop = s_rov + kh*128;
        const float* Wm = W_mean + (size_t)(256 + kh*128)*Udim + col;
        float acc = 0.f;
        #pragma unroll 8
        for (int i=0;i<128;i++)
            acc = fmaf(rop[i], Wm[(size_t)i*Udim], acc);
        s_part[kh][col] = acc;

        float cb = s_rov[t]*W_beta[256+t];
        float cs = s_rov[t]*W_sw[256+t];
        #pragma unroll
        for (int off=32; off>=1; off>>=1){
            cb += __shfl_down(cb, off);
            cs += __shfl_down(cs, off);
        }
        if (lane == 0){ s_red[0][wid] = cb; s_red[1][wid] = cs; }
    }
    __syncthreads();
    if (t == 0){
        float db  = s_red[0][0]+s_red[0][1]+s_red[0][2]+s_red[0][3] + ws_bh[b] + b_beta[0];
        float dsw = s_red[1][0]+s_red[1][1]+s_red[1][2]+s_red[1][3] + ws_sh[b] + b_sw[0];
        float beta = 0.05f + 0.945f*sigm(db);
        float swp = sigm(dsw);
        float swf = (swp > 0.5f) ? 1.0f : 0.0f;
        if (step_in_macro[b] == 0) swf = 1.0f;
        out_beta[b]  = beta;
        out_swp[b]   = swp;
        out_switch[b]= swf;
        s_beff = beta*(1.0f - swf);
    }
    __syncthreads();
    if (t < 128){
        float mean = ws_meanh[(size_t)b*Udim + t] + s_part[0][t] + s_part[1][t] + b_mean[t];
        size_t o = (size_t)b*Udim + t;
        out_uprop[o] = mean;
        float be = s_beff;
        out_uint[o] = be*u_int_prev[o] + (1.0f-be)*mean;
    }
}

extern "C" void kernel_launch(void* const* d_in, const int* in_sizes, int n_in,
                              void* d_out, int out_size, void* d_ws, size_t ws_size,
                              hipStream_t stream)
{
    const float* h_prev   = (const float*)d_in[0];
    const float* keys     = (const float*)d_in[1];
    const float* vals     = (const float*)d_in[2];
    const float* age      = (const float*)d_in[3];
    const float* strength = (const float*)d_in[4];
    const float* obs      = (const float*)d_in[5];
    const float* ssum     = (const float*)d_in[6];
    const float* u_int_prev = (const float*)d_in[7];
    const int*   step     = (const int*)d_in[8];
    const float* W_obs    = (const float*)d_in[9];
    const float* b_obs    = (const float*)d_in[10];
    const float* W_ssum   = (const float*)d_in[11];
    const float* b_ssum   = (const float*)d_in[12];
    const float* Wi       = (const float*)d_in[13];
    const float* bi       = (const float*)d_in[14];
    const float* Wh       = (const float*)d_in[15];
    const float* bhn      = (const float*)d_in[16];
    const float* W_gate   = (const float*)d_in[17];
    const float* b_gate   = (const float*)d_in[18];
    const float* W_mean   = (const float*)d_in[19];
    const float* b_mean   = (const float*)d_in[20];
    const float* W_beta   = (const float*)d_in[22];
    const float* b_beta   = (const float*)d_in[23];
    const float* W_sw     = (const float*)d_in[24];
    const float* b_sw     = (const float*)d_in[25];

    float* out = (float*)d_out;
    float* out_h    = out;                       // 2048*256
    float* out_kn   = out_h   + 524288;          // 2048*32*256
    float* out_vn   = out_kn  + 16777216;
    float* out_age  = out_vn  + 16777216;        // 2048*32
    float* out_str  = out_age + 65536;
    float* out_up   = out_str + 65536;           // 2048*128
    float* out_sw   = out_up  + 262144;          // 2048
    float* out_ui   = out_sw  + 2048;            // 2048*128
    float* out_beta = out_ui  + 262144;          // 2048
    float* out_swp  = out_beta+ 2048;            // 2048

    float* ws = (float*)d_ws;
    float* ws_invn  = ws;                        // B
    float* ws_wstr  = ws + Bdim;                 // B
    float* ws_bh    = ws + 2*Bdim;               // B
    float* ws_sh    = ws + 3*Bdim;               // B
    float* ws_meanh = ws + 4*Bdim;               // B*128

    // scratch reusing output regions (consumed before kBC overwrites them)
    float* ws_xin = out_vn;                      // B*256 floats, overwritten by kBC later
    float* ws_g   = out_kn;                      // B*1024 floats, overwritten by kBC later

    kA1<<<Bdim/4, 256, 0, stream>>>(obs, ssum, W_obs, b_obs, W_ssum, b_ssum, ws_xin);
    kG2<<<512, 256, 0, stream>>>(ws_xin, h_prev, Wi, Wh, ws_g);
    kA3<<<Bdim/4, 256, 0, stream>>>(ws_g, h_prev, bi, bhn, W_gate, b_gate,
                                    W_beta, W_sw, W_mean,
                                    out_h, ws_invn, ws_wstr, ws_bh, ws_sh, ws_meanh);
    kBC<<<Bdim, 256, 0, stream>>>(keys, vals, age, strength, out_h,
                                  ws_invn, ws_wstr, ws_bh, ws_sh, ws_meanh,
                                  u_int_prev, step, W_mean, b_mean,
                                  W_beta, b_beta, W_sw, b_sw,
                                  out_kn, out_vn, out_age, out_str,
                                  out_up, out_sw, out_ui, out_beta, out_swp);
}